// Round 10
// baseline (460.225 us; speedup 1.0000x reference)
//
#include <hip/hip_runtime.h>

namespace {
constexpr int CH = 640, HW = 25, MS = 125;
constexpr int CHW = CH * HW;    // 16000
constexpr float GAMMA = 20.f, GAMMA2 = 10.f;
constexpr float EPS = 1e-12f;
}

// Shot-mean + L2-normalize (over c) + transpose to sup_t[b][nk][c]. (proven)
__global__ __launch_bounds__(256)
void prep_sup_kernel(const float* __restrict__ sup, float* __restrict__ sup_t) {
  __shared__ __align__(16) float m[CHW];   // mean tile [c][k]
  __shared__ float inv[HW];
  const int bn = blockIdx.x;               // b*5 + n
  const float* base = sup + (size_t)(bn / 5) * (25 * CHW)
                          + (size_t)(bn % 5) * (5 * CHW);
  for (int idx = threadIdx.x; idx < CHW; idx += 256) {
    float s = 0.f;
    #pragma unroll
    for (int sh = 0; sh < 5; ++sh) s += base[sh * CHW + idx];
    m[idx] = s * 0.2f;
  }
  __syncthreads();
  {
    int i = threadIdx.x >> 3, s8 = threadIdx.x & 7;
    if (i < HW) {
      float p = 0.f;
      for (int c = s8; c < CH; c += 8) { float v = m[c * HW + i]; p += v * v; }
      p += __shfl_xor(p, 1); p += __shfl_xor(p, 2); p += __shfl_xor(p, 4);
      if (s8 == 0) inv[i] = rsqrtf(p + EPS);
    }
  }
  __syncthreads();
  float* outp = sup_t + (size_t)bn * CHW;  // [nk][c], coalesced writes
  for (int idx = threadIdx.x; idx < CHW; idx += 256) {
    int k = idx / CH, c = idx - k * CH;
    outp[idx] = m[c * HW + k] * inv[k];
  }
}

// One block per (b, 3-query group): 75x125 S GEMM (5x8 reg tiles) ->
// per-query softmax/BA -> batched wave-parallel f64 Katz solves -> outputs.
__global__ __launch_bounds__(256)
void melmask_kernel(const float* __restrict__ qry, const float* __restrict__ sup_t,
                    float* __restrict__ out) {
  __shared__ __align__(16) float pool[3456]; // atile[16][84] | btile[16][132]; Qm overlay
  __shared__ __align__(16) float Sld[3125];  // one query's S[r][col]; in-place P
  __shared__ double Msol3[2025];             // 3 systems x (25x26 aug, stride 27)
  __shared__ float rmaxs[80], rsis[80], invq_s[80];
  __shared__ float x3[96];                   // [qq][32] solution
  __shared__ float kqv[96];                  // [qq][32] kq values
  __shared__ float ksf3[384];                // [qq][128] ks accumulators
  __shared__ float kqsum[3], ksinv[24];      // [qq], [qq*8+n]

  float* atile = pool;                       // [k][84]
  float* btile = pool + 1344;                // [k][132]
  float* Qm    = pool;                       // overlays staging after GEMM

  const int tid = threadIdx.x;
  // XCD swizzle: 800 = 8*100, bijective; same-XCD blocks share consecutive b's.
  const int Bl = (blockIdx.x & 7) * 100 + (blockIdx.x >> 3);
  const int b = Bl / 25, qg = Bl - 25 * b;
  const float* qbase = qry + ((size_t)b * 75 + (size_t)qg * 3) * CHW;
  const float* sbase = sup_t + (size_t)b * (MS * CH);
  const int ty = tid >> 4, tx = tid & 15;    // rows 5ty+u (u<5), cols {4tx+v, 64+4tx+v}

  float acc[5][8];
  #pragma unroll
  for (int u = 0; u < 5; ++u)
    #pragma unroll
    for (int e = 0; e < 8; ++e) acc[u][e] = 0.f;
  float npart = 0.f;

  for (int c0 = 0; c0 < CH; c0 += 16) {
    __syncthreads();                         // protect staging from prev readers
    #pragma unroll
    for (int mm = 0; mm < 5; ++mm) {         // A: 16k x 80row (75 real)
      int idx = tid + 256 * mm;              // < 1280
      int k = idx / 80, row = idx - 80 * k;
      float v = 0.f;
      if (row < 75) {
        int qq = row / 25, i = row - 25 * qq;
        v = qbase[(size_t)qq * CHW + (size_t)(c0 + k) * 25 + i];
      }
      atile[k * 84 + row] = v;
    }
    #pragma unroll
    for (int mm = 0; mm < 2; ++mm) {         // B: 16k x 128col (transpose via float4)
      int idx = tid + 256 * mm;
      int col = idx >> 2, kq4 = idx & 3;
      float4 v = make_float4(0.f, 0.f, 0.f, 0.f);
      if (col < MS) v = *(const float4*)(sbase + (size_t)col * CH + c0 + 4 * kq4);
      btile[(4 * kq4 + 0) * 132 + col] = v.x;
      btile[(4 * kq4 + 1) * 132 + col] = v.y;
      btile[(4 * kq4 + 2) * 132 + col] = v.z;
      btile[(4 * kq4 + 3) * 132 + col] = v.w;
    }
    __syncthreads();
    if (tid < 80) {                          // query inv-norm accumulation
      #pragma unroll
      for (int k = 0; k < 16; ++k) { float v = atile[k * 84 + tid]; npart += v * v; }
    }
    #pragma unroll
    for (int k = 0; k < 16; ++k) {
      float a[5];
      #pragma unroll
      for (int u = 0; u < 5; ++u) a[u] = atile[k * 84 + 5 * ty + u];
      const float4 b0 = *(const float4*)&btile[k * 132 + 4 * tx];
      const float4 b1 = *(const float4*)&btile[k * 132 + 64 + 4 * tx];
      #pragma unroll
      for (int u = 0; u < 5; ++u) {
        acc[u][0] += a[u] * b0.x; acc[u][1] += a[u] * b0.y;
        acc[u][2] += a[u] * b0.z; acc[u][3] += a[u] * b0.w;
        acc[u][4] += a[u] * b1.x; acc[u][5] += a[u] * b1.y;
        acc[u][6] += a[u] * b1.z; acc[u][7] += a[u] * b1.w;
      }
    }
  }
  if (tid < 75) invq_s[tid] = rsqrtf(npart + EPS);
  __syncthreads();

  // ---- per-query: scatter S -> col softmax -> row softmax -> BA -> Msol3[qq] ----
  for (int qq = 0; qq < 3; ++qq) {
    const int r0 = 25 * qq;
    #pragma unroll
    for (int u = 0; u < 5; ++u) {
      const int row = 5 * ty + u;
      if (row >= r0 && row < r0 + 25) {
        const int r = row - r0;
        const float iv = invq_s[row];
        #pragma unroll
        for (int h = 0; h < 2; ++h)
          #pragma unroll
          for (int v = 0; v < 4; ++v) {
            const int col = 64 * h + 4 * tx + v;
            if (col < MS) Sld[r * MS + col] = acc[u][4 * h + v] * iv;
          }
      }
    }
    __syncthreads();

    // column softmax with GAMMA2 -> Qm[col][i]
    if (tid < MS) {
      float mx = -1e30f;
      #pragma unroll
      for (int i = 0; i < HW; ++i) mx = fmaxf(mx, Sld[i * MS + tid]);
      float e[HW]; float sum = 0.f;
      #pragma unroll
      for (int i = 0; i < HW; ++i) { e[i] = __expf(GAMMA2 * (Sld[i * MS + tid] - mx)); sum += e[i]; }
      float is = 1.f / sum;
      #pragma unroll
      for (int i = 0; i < HW; ++i) Qm[tid * HW + i] = e[i] * is;
    }
    __syncthreads();

    // row softmax with GAMMA, in place -> P; persist per-row stats
    {
      int i = tid >> 3, s8 = tid & 7;
      if (i < HW) {
        float mx = -1e30f;
        for (int j = s8; j < MS; j += 8) mx = fmaxf(mx, Sld[i * MS + j]);
        mx = fmaxf(mx, __shfl_xor(mx, 1));
        mx = fmaxf(mx, __shfl_xor(mx, 2));
        mx = fmaxf(mx, __shfl_xor(mx, 4));
        float sum = 0.f;
        for (int j = s8; j < MS; j += 8) {
          float e = __expf(GAMMA * (Sld[i * MS + j] - mx));
          Sld[i * MS + j] = e; sum += e;
        }
        sum += __shfl_xor(sum, 1); sum += __shfl_xor(sum, 2); sum += __shfl_xor(sum, 4);
        float is = 1.f / sum;
        for (int j = s8; j < MS; j += 8) Sld[i * MS + j] *= is;
        if (s8 == 0) { rmaxs[r0 + i] = mx; rsis[r0 + i] = is; }
      }
    }
    __syncthreads();

    // BA (+ B*1 via i2==25) -> Msol3[qq]  (no alias with Qm/Sld)
    #pragma unroll
    for (int t = 0; t < 3; ++t) {
      const int pp = tid + 256 * t;
      if (pp < 650) {
        const int i = pp / 26, i2 = pp - 26 * i;
        float s = 0.f;
        if (i2 < 25) {
          for (int j = 0; j < MS; ++j) s += Qm[j * HW + i] * Sld[i2 * MS + j];
        } else {
          for (int j = 0; j < MS; ++j) s += Qm[j * HW + i];
        }
        if (i2 < 25) Msol3[qq * 675 + i * 27 + i2] = (i == i2 ? 1.0 : 0.0) - 0.998001 * (double)s;
        else         Msol3[qq * 675 + i * 27 + 25] = 1.0 + 0.999 * (double)s;
      }
    }
    __syncthreads();   // Sld/Qm reuse fence for next query
  }

  // ---- batched Gaussian elimination: wave w solves system w (no pivoting) ----
  const int wv = tid >> 6, lane = tid & 63;
  for (int k = 0; k < 24; ++k) {
    if (wv < 3) {
      double* M = Msol3 + 675 * wv;
      const double invp = 1.0 / M[k * 27 + k];
      const int jj = k + 1 + (lane & 31);
      for (int i = k + 1 + (lane >> 5); i < HW; i += 2) {
        const double f = M[i * 27 + k] * invp;
        if (jj <= HW) M[i * 27 + jj] -= f * M[k * 27 + jj];
      }
    }
    __syncthreads();
  }
  for (int k = 24; k >= 0; --k) {
    if (wv < 3) {
      double* M = Msol3 + 675 * wv;
      const double xk = M[k * 27 + 25] / M[k * 27 + k];
      if (lane == 0) x3[wv * 32 + k] = (float)xk;
      if (lane < k) M[lane * 27 + 25] -= M[lane * 27 + k] * xk;
    }
    __syncthreads();
  }

  // ---- outputs ----
  if (tid < 75) {
    const int qq = tid / 25, i = tid - 25 * qq;
    kqv[qq * 32 + i] = x3[qq * 32 + i] - 1.0f;
  }
  ksf3[tid] = 0.f;
  if (tid < 128) ksf3[256 + tid] = 0.f;
  __syncthreads();

  // ks recompute from registers: ks[qq][col] = sum_i P[row][col] * x[qq][i]
  #pragma unroll
  for (int u = 0; u < 5; ++u) {
    const int row = 5 * ty + u;
    if (row < 75) {
      const int qq = row / 25, i = row - 25 * qq;
      const float iv = invq_s[row], rm = rmaxs[row], rs = rsis[row];
      const float xv = x3[qq * 32 + i];
      #pragma unroll
      for (int h = 0; h < 2; ++h)
        #pragma unroll
        for (int v = 0; v < 4; ++v) {
          const int col = 64 * h + 4 * tx + v;
          if (col < MS) {
            const float e = __expf(GAMMA * (acc[u][4 * h + v] * iv - rm)) * rs;
            atomicAdd(&ksf3[qq * 128 + col], e * xv);
          }
        }
    }
  }
  if (tid < 3) {
    float s = 0.f;
    #pragma unroll
    for (int i = 0; i < HW; ++i) s += kqv[tid * 32 + i];
    kqsum[tid] = s;
  }
  __syncthreads();
  if (tid < 15) {
    const int qq = tid / 5, n = tid - 5 * qq;
    float s = 0.f;
    #pragma unroll
    for (int j = 0; j < HW; ++j) s += ksf3[qq * 128 + n * 25 + j];
    ksinv[qq * 8 + n] = 1.f / s;
  }
  __syncthreads();
  if (tid < 75) {
    const int qq = tid / 25, i = tid - 25 * qq;
    const int bq = b * 75 + qg * 3 + qq;
    out[(size_t)bq * HW + i] = kqv[qq * 32 + i] / kqsum[qq];
  }
  #pragma unroll
  for (int t = 0; t < 2; ++t) {
    const int idx = tid + 256 * t;
    if (idx < 375) {
      const int qq = idx / 125, col = idx - 125 * qq;
      const int bq = b * 75 + qg * 3 + qq;
      out[60000 + (size_t)bq * MS + col] = ksf3[qq * 128 + col] * ksinv[qq * 8 + col / 25];
    }
  }
}

extern "C" void kernel_launch(void* const* d_in, const int* in_sizes, int n_in,
                              void* d_out, int out_size, void* d_ws, size_t ws_size,
                              hipStream_t stream) {
  const float* sup = (const float*)d_in[0];
  const float* qry = (const float*)d_in[1];
  float* outp = (float*)d_out;
  float* sup_t = (float*)d_ws;             // 32*125*640*4 = 10.24 MB (proven fit)
  prep_sup_kernel<<<160, 256, 0, stream>>>(sup, sup_t);
  melmask_kernel<<<800, 256, 0, stream>>>(qry, sup_t, outp);
}